// Round 7
// baseline (339.053 us; speedup 1.0000x reference)
//
#include <hip/hip_runtime.h>
#include <hip/hip_fp16.h>
#include <math.h>

#define F1 128
#define C2N 8
#define SLOPE 0.2f
#define EPSBN 1e-5f

__device__ __forceinline__ unsigned fenc(float f){
  unsigned u = __float_as_uint(f);
  return (u & 0x80000000u) ? ~u : (u | 0x80000000u);
}
__device__ __forceinline__ float fdec(unsigned u){
  return (u & 0x80000000u) ? __uint_as_float(u & 0x7FFFFFFFu) : __uint_as_float(~u);
}
__device__ __forceinline__ float2 h2f2(unsigned u){
  __half2 h = *(__half2*)&u;
  return __half22float2(h);
}

// ---- BatchNorm stats ----
__global__ __launch_bounds__(128) void k_bn_stats(const float* __restrict__ x,
    float* __restrict__ sum, float* __restrict__ sumsq, int n){
  int f = threadIdx.x;
  float s = 0.f, ss = 0.f;
  for (int r = blockIdx.x; r < n; r += gridDim.x){
    float v = x[(size_t)r*F1 + f];
    s += v; ss += v*v;
  }
  atomicAdd(&sum[f], s);
  atomicAdd(&sumsq[f], ss);
}

__global__ __launch_bounds__(128) void k_bn_final(const float* __restrict__ sum,
    const float* __restrict__ sumsq, const float* __restrict__ gamma,
    const float* __restrict__ beta, float* __restrict__ ab, int n){
  int f = threadIdx.x;
  float inv_n = 1.f / (float)n;
  float mean = sum[f] * inv_n;
  float var  = sumsq[f] * inv_n - mean*mean;
  float inv  = rsqrtf(var + EPSBN);
  float a = inv * gamma[f];
  ab[f]      = a;
  ab[F1 + f] = beta[f] - mean*a;
}

// ---- normalize + x@W1 (128x128) + al1/ar1; h1 fp16 ----
__global__ __launch_bounds__(128) void k_gemm1(const float* __restrict__ x,
    const float* __restrict__ ab, const float* __restrict__ W1,
    const float* __restrict__ asrc, const float* __restrict__ adst,
    __half* __restrict__ h1, float* __restrict__ al, float* __restrict__ ar, int n){
  const int j  = threadIdx.x;
  const int r0 = blockIdx.x * 8;
  __shared__ float xs[8][F1];
  float A = ab[j], B = ab[F1 + j];
  int nr = n - r0; if (nr > 8) nr = 8;
  for (int rr = 0; rr < nr; ++rr)
    xs[rr][j] = x[(size_t)(r0+rr)*F1 + j] * A + B;
  __syncthreads();
  float acc[8] = {0,0,0,0,0,0,0,0};
  for (int k = 0; k < F1; ++k){
    float w = W1[k*F1 + j];
    #pragma unroll
    for (int rr = 0; rr < 8; ++rr) acc[rr] += xs[rr][k] * w;
  }
  float as = asrc[j], ad = adst[j];
  for (int rr = 0; rr < nr; ++rr){
    float hv = acc[rr];
    h1[(size_t)(r0+rr)*F1 + j] = __float2half(hv);
    float vs = hv*as, vd = hv*ad;
    #pragma unroll
    for (int mk = 1; mk < 32; mk <<= 1){
      vs += __shfl_xor(vs, mk);
      vd += __shfl_xor(vd, mk);
    }
    if ((j & 31) == 0){
      al[(r0+rr)*4 + (j>>5)] = vs;
      ar[(r0+rr)*4 + (j>>5)] = vd;
    }
  }
}

// ---- global column max ----
__global__ __launch_bounds__(256) void k_colmax(const float* __restrict__ v,
    unsigned* __restrict__ out, int total, int H){
  int tid = blockIdx.x*256 + threadIdx.x;
  int stride = gridDim.x*256;
  float mx = -1e30f;
  for (int i = tid; i < total; i += stride)
    mx = fmaxf(mx, v[i]);
  for (int m = H; m < 64; m <<= 1)
    mx = fmaxf(mx, __shfl_xor(mx, m));
  int lane = threadIdx.x & 63;
  if (lane < H) atomicMax(&out[lane], fenc(mx));
}

// ---- dst-degree histogram ----
__global__ __launch_bounds__(256) void k_deg(const int* __restrict__ ei,
    int* __restrict__ deg, int E, int Etot){
  int e = blockIdx.x*blockDim.x + threadIdx.x;
  if (e >= Etot) return;
  int d = (e < E) ? ei[E + e] : (e - E);
  atomicAdd(&deg[d], 1);
}

// ---- scan A: pad degrees to mult-of-16, local exclusive scan + block sum ----
__global__ __launch_bounds__(256) void k_scan_a(const int* __restrict__ deg,
    int* __restrict__ rowptr, int* __restrict__ bsum, int n){
  int t = threadIdx.x;
  int base = blockIdx.x*1024 + t*4;
  int4 v = {0,0,0,0};
  if (base + 3 < n) v = *(const int4*)&deg[base];
  else {
    if (base   < n) v.x = deg[base];
    if (base+1 < n) v.y = deg[base+1];
    if (base+2 < n) v.z = deg[base+2];
    if (base+3 < n) v.w = deg[base+3];
  }
  v.x = (v.x+15)&~15; v.y = (v.y+15)&~15; v.z = (v.z+15)&~15; v.w = (v.w+15)&~15;
  int s = v.x + v.y + v.z + v.w;
  __shared__ int ls[256];
  ls[t] = s; __syncthreads();
  for (int off = 1; off < 256; off <<= 1){
    int u = (t >= off) ? ls[t-off] : 0;
    __syncthreads();
    ls[t] += u;
    __syncthreads();
  }
  int ex = ls[t] - s;
  if (t == 255) bsum[blockIdx.x] = ls[255];
  int4 w;
  w.x = ex;
  w.y = ex + v.x;
  w.z = w.y + v.y;
  w.w = w.z + v.z;
  if (base + 3 < n) *(int4*)&rowptr[base] = w;
  else {
    if (base   < n) rowptr[base]   = w.x;
    if (base+1 < n) rowptr[base+1] = w.y;
    if (base+2 < n) rowptr[base+2] = w.z;
    if (base+3 < n) rowptr[base+3] = w.w;
  }
}

// ---- scan C: add block offsets, mirror cursor, write rowptr[n] ----
__global__ __launch_bounds__(256) void k_scan_c(int* __restrict__ rowptr,
    int* __restrict__ cursor, const int* __restrict__ bsum, int n){
  int t = threadIdx.x;
  __shared__ int s_boff;
  if (t < 64){
    int b = blockIdx.x;
    int val = 0;
    for (int i = t; i < b; i += 64) val += bsum[i];
    #pragma unroll
    for (int m = 1; m < 64; m <<= 1) val += __shfl_xor(val, m);
    if (t == 0) s_boff = val;
  }
  __syncthreads();
  int boff = s_boff;
  if (t == 0 && blockIdx.x == gridDim.x - 1)
    rowptr[n] = boff + bsum[blockIdx.x];
  int base = blockIdx.x*1024 + t*4;
  if (base + 3 < n){
    int4 v = *(int4*)&rowptr[base];
    v.x += boff; v.y += boff; v.z += boff; v.w += boff;
    *(int4*)&rowptr[base] = v;
    *(int4*)&cursor[base] = v;
  } else {
    for (int k = 0; k < 4; ++k)
      if (base + k < n){
        int v = rowptr[base+k] + boff;
        rowptr[base+k] = v; cursor[base+k] = v;
      }
  }
}

// ---- CSR fill: src + dst ----
__global__ __launch_bounds__(256) void k_fill(const int* __restrict__ ei,
    int* __restrict__ cursor, int* __restrict__ csr_src, int* __restrict__ csr_dst,
    int E, int Etot){
  int e = blockIdx.x*blockDim.x + threadIdx.x;
  if (e >= Etot) return;
  int s = (e < E) ? ei[e]     : (e - E);
  int d = (e < E) ? ei[E + e] : (e - E);
  int pos = atomicAdd(&cursor[d], 1);
  csr_src[pos] = s;
  csr_dst[pos] = d;
}

// ---- layer-1 edge weights (4 heads), fp16, pads -> 0 ----
__global__ __launch_bounds__(256) void k_edge_w1(const int* __restrict__ csr_src,
    const int* __restrict__ csr_dst, const float* __restrict__ al,
    const float* __restrict__ ar, const unsigned* __restrict__ almax,
    __half* __restrict__ w1, int EPST){
  int p = blockIdx.x*256 + threadIdx.x;
  if (p >= EPST) return;
  int d = csr_dst[p];
  if (d < 0){
    __half z = __float2half(0.f);
    w1[p] = z; w1[(size_t)EPST + p] = z;
    w1[2*(size_t)EPST + p] = z; w1[3*(size_t)EPST + p] = z;
    return;
  }
  int s = csr_src[p];
  float4 als = *(const float4*)&al[(size_t)s*4];
  float4 ard = *(const float4*)&ar[(size_t)d*4];
  float va[4] = {als.x+ard.x, als.y+ard.y, als.z+ard.z, als.w+ard.w};
  float ma[4] = {fdec(almax[0])+ard.x, fdec(almax[1])+ard.y,
                 fdec(almax[2])+ard.z, fdec(almax[3])+ard.w};
  #pragma unroll
  for (int h = 0; h < 4; ++h){
    float v = va[h];  v  = v  > 0.f ? v  : SLOPE*v;
    float ub = ma[h]; ub = ub > 0.f ? ub : SLOPE*ub;
    w1[(size_t)h*EPST + p] = __float2half(__expf(v - ub));
  }
}

// ---- layer-2 edge weights (1 head) ----
__global__ __launch_bounds__(256) void k_edge_w2(const int* __restrict__ csr_src,
    const int* __restrict__ csr_dst, const float* __restrict__ al,
    const float* __restrict__ ar, const unsigned* __restrict__ almax,
    __half* __restrict__ w2, int EPST){
  int p = blockIdx.x*256 + threadIdx.x;
  if (p >= EPST) return;
  int d = csr_dst[p];
  if (d < 0){ w2[p] = __float2half(0.f); return; }
  int s = csr_src[p];
  float ardv = ar[d];
  float v = al[s] + ardv; v = v > 0.f ? v : SLOPE*v;
  float ub = fdec(almax[0]) + ardv; ub = ub > 0.f ? ub : SLOPE*ub;
  w2[p] = __float2half(__expf(v - ub));
}

// ---- layer-1 GAT: 1 wave/node, uniform chunk loads, no shuffles ----
#define LD1(S) __half22float2(*(const __half2*)&h1[((size_t)(S)<<7) + f0])
__global__ __launch_bounds__(256) void k_gat1(const int* __restrict__ rowptr,
    const int* __restrict__ csr_src, const __half* __restrict__ w1,
    const __half* __restrict__ h1, const float* __restrict__ b1,
    __half* __restrict__ x1, int n, int EPST){
  int node = blockIdx.x*4 + (threadIdx.x >> 6);
  if (node >= n) return;
  int lane = threadIdx.x & 63;
  int h  = lane >> 4;
  int f0 = lane*2;
  int beg = rowptr[node], end = rowptr[node+1];
  const __half* wp = w1 + (size_t)h*EPST;
  float den = 0.f, a0 = 0.f, a1 = 0.f;
  for (int c = beg; c < end; c += 16){
    int4 sA = *(const int4*)(csr_src + c);
    int4 sB = *(const int4*)(csr_src + c + 4);
    int4 sC = *(const int4*)(csr_src + c + 8);
    int4 sD = *(const int4*)(csr_src + c + 12);
    uint4 wa = *(const uint4*)(wp + c);
    uint4 wb = *(const uint4*)(wp + c + 8);
    float2 w01 = h2f2(wa.x), w23 = h2f2(wa.y), w45 = h2f2(wa.z), w67 = h2f2(wa.w);
    float2 w89 = h2f2(wb.x), wab = h2f2(wb.y), wcd = h2f2(wb.z), wef = h2f2(wb.w);
    den += ((w01.x+w01.y)+(w23.x+w23.y)) + ((w45.x+w45.y)+(w67.x+w67.y))
         + ((w89.x+w89.y)+(wab.x+wab.y)) + ((wcd.x+wcd.y)+(wef.x+wef.y));
    float2 g0 = LD1(sA.x), g1 = LD1(sA.y), g2 = LD1(sA.z), g3 = LD1(sA.w);
    float2 g4 = LD1(sB.x), g5 = LD1(sB.y), g6 = LD1(sB.z), g7 = LD1(sB.w);
    float2 g8 = LD1(sC.x), g9 = LD1(sC.y), gA = LD1(sC.z), gB = LD1(sC.w);
    float2 gC = LD1(sD.x), gD = LD1(sD.y), gE = LD1(sD.z), gF = LD1(sD.w);
    a0 += w01.x*g0.x; a1 += w01.x*g0.y;
    a0 += w01.y*g1.x; a1 += w01.y*g1.y;
    a0 += w23.x*g2.x; a1 += w23.x*g2.y;
    a0 += w23.y*g3.x; a1 += w23.y*g3.y;
    a0 += w45.x*g4.x; a1 += w45.x*g4.y;
    a0 += w45.y*g5.x; a1 += w45.y*g5.y;
    a0 += w67.x*g6.x; a1 += w67.x*g6.y;
    a0 += w67.y*g7.x; a1 += w67.y*g7.y;
    a0 += w89.x*g8.x; a1 += w89.x*g8.y;
    a0 += w89.y*g9.x; a1 += w89.y*g9.y;
    a0 += wab.x*gA.x; a1 += wab.x*gA.y;
    a0 += wab.y*gB.x; a1 += wab.y*gB.y;
    a0 += wcd.x*gC.x; a1 += wcd.x*gC.y;
    a0 += wcd.y*gD.x; a1 += wcd.y*gD.y;
    a0 += wef.x*gE.x; a1 += wef.x*gE.y;
    a0 += wef.y*gF.x; a1 += wef.y*gF.y;
  }
  float inv = 1.f / (den + 1e-16f);
  float v0 = a0*inv + b1[f0];
  float v1 = a1*inv + b1[f0+1];
  v0 = v0 > 0.f ? v0 : expm1f(v0);
  v1 = v1 > 0.f ? v1 : expm1f(v1);
  *(__half2*)&x1[((size_t)node<<7) + f0] = __floats2half2_rn(v0, v1);
}

// ---- x1@W2 (128x8) + al2/ar2 ----
__global__ __launch_bounds__(256) void k_gemm2(const __half* __restrict__ x1,
    const float* __restrict__ W2, const float* __restrict__ as2,
    const float* __restrict__ ad2, float* __restrict__ h2,
    float* __restrict__ al2, float* __restrict__ ar2, int n){
  int r = blockIdx.x*32 + (threadIdx.x >> 3);
  int j = threadIdx.x & 7;
  if (r >= n) return;
  const __half* xr = x1 + (size_t)r*F1;
  float a = 0.f;
  for (int k = 0; k < F1; k += 2){
    float2 xv = __half22float2(*(const __half2*)&xr[k]);
    a += xv.x*W2[k*C2N + j] + xv.y*W2[(k+1)*C2N + j];
  }
  h2[(size_t)r*C2N + j] = a;
  float vs = a*as2[j], vd = a*ad2[j];
  #pragma unroll
  for (int mk = 1; mk < 8; mk <<= 1){
    vs += __shfl_xor(vs, mk);
    vd += __shfl_xor(vd, mk);
  }
  if (j == 0){ al2[r] = vs; ar2[r] = vd; }
}

// ---- layer-2 GAT: 8 lanes/node, uniform chunk loads, no shuffles ----
__global__ __launch_bounds__(256) void k_gat2(const int* __restrict__ rowptr,
    const int* __restrict__ csr_src, const __half* __restrict__ w2,
    const float* __restrict__ h2, const float* __restrict__ b2,
    const int* __restrict__ batch, float* __restrict__ pooled,
    float* __restrict__ cnt, int n){
  int node = blockIdx.x*32 + (threadIdx.x >> 3);
  if (node >= n) return;
  int sub = threadIdx.x & 7;
  int beg = rowptr[node], end = rowptr[node+1];
  float den = 0.f, acc = 0.f;
  for (int c = beg; c < end; c += 16){
    int4 sA = *(const int4*)(csr_src + c);
    int4 sB = *(const int4*)(csr_src + c + 4);
    int4 sC = *(const int4*)(csr_src + c + 8);
    int4 sD = *(const int4*)(csr_src + c + 12);
    uint4 wa = *(const uint4*)(w2 + c);
    uint4 wb = *(const uint4*)(w2 + c + 8);
    float2 w01 = h2f2(wa.x), w23 = h2f2(wa.y), w45 = h2f2(wa.z), w67 = h2f2(wa.w);
    float2 w89 = h2f2(wb.x), wab = h2f2(wb.y), wcd = h2f2(wb.z), wef = h2f2(wb.w);
    den += ((w01.x+w01.y)+(w23.x+w23.y)) + ((w45.x+w45.y)+(w67.x+w67.y))
         + ((w89.x+w89.y)+(wab.x+wab.y)) + ((wcd.x+wcd.y)+(wef.x+wef.y));
    acc += w01.x * h2[((size_t)sA.x<<3) + sub];
    acc += w01.y * h2[((size_t)sA.y<<3) + sub];
    acc += w23.x * h2[((size_t)sA.z<<3) + sub];
    acc += w23.y * h2[((size_t)sA.w<<3) + sub];
    acc += w45.x * h2[((size_t)sB.x<<3) + sub];
    acc += w45.y * h2[((size_t)sB.y<<3) + sub];
    acc += w67.x * h2[((size_t)sB.z<<3) + sub];
    acc += w67.y * h2[((size_t)sB.w<<3) + sub];
    acc += w89.x * h2[((size_t)sC.x<<3) + sub];
    acc += w89.y * h2[((size_t)sC.y<<3) + sub];
    acc += wab.x * h2[((size_t)sC.z<<3) + sub];
    acc += wab.y * h2[((size_t)sC.w<<3) + sub];
    acc += wcd.x * h2[((size_t)sD.x<<3) + sub];
    acc += wcd.y * h2[((size_t)sD.y<<3) + sub];
    acc += wef.x * h2[((size_t)sD.z<<3) + sub];
    acc += wef.y * h2[((size_t)sD.w<<3) + sub];
  }
  float o = acc / (den + 1e-16f) + b2[sub];
  int g = batch[node];
  atomicAdd(&pooled[g*C2N + sub], o);
  if (sub == 0) atomicAdd(&cnt[g], 1.f);
}

// ---- mean + log_softmax ----
__global__ __launch_bounds__(256) void k_final(const float* __restrict__ pooled,
    const float* __restrict__ cnt, float* __restrict__ out, int G){
  int g = blockIdx.x*blockDim.x + threadIdx.x;
  if (g >= G) return;
  float c = cnt[g]; c = c > 1.f ? c : 1.f;
  float p[8]; float mx = -1e30f;
  #pragma unroll
  for (int j = 0; j < 8; ++j){ p[j] = pooled[g*8+j] / c; mx = fmaxf(mx, p[j]); }
  float s = 0.f;
  #pragma unroll
  for (int j = 0; j < 8; ++j) s += expf(p[j]-mx);
  float lse = mx + logf(s);
  #pragma unroll
  for (int j = 0; j < 8; ++j) out[g*8+j] = p[j] - lse;
}

extern "C" void kernel_launch(void* const* d_in, const int* in_sizes, int n_in,
                              void* d_out, int out_size, void* d_ws, size_t ws_size,
                              hipStream_t stream){
  const float* x    = (const float*)d_in[0];
  const float* gam  = (const float*)d_in[1];
  const float* bet  = (const float*)d_in[2];
  const float* W1   = (const float*)d_in[3];
  const float* as1  = (const float*)d_in[4];
  const float* ad1  = (const float*)d_in[5];
  const float* b1   = (const float*)d_in[6];
  const float* W2   = (const float*)d_in[7];
  const float* as2  = (const float*)d_in[8];
  const float* ad2  = (const float*)d_in[9];
  const float* b2   = (const float*)d_in[10];
  const int*   ei   = (const int*)d_in[11];
  const int*   batch= (const int*)d_in[12];

  int N = in_sizes[0] / F1;
  int E = in_sizes[11] / 2;
  int G = out_size / C2N;
  int Etot = E + N;
  int nb = (N + 1023) / 1024;
  int EPST = (E + 16*N + 63) & ~63;   // upper bound on padded CSR size

  char* base = (char*)d_ws;
  auto alloc = [&](size_t bytes)->char*{
    char* p = base; base += (bytes + 15) & ~15ull; return p;
  };

  // ---- region A: zeroed every launch ----
  char* A0 = base;
  float*    sum     = (float*)alloc(128*4);
  float*    sumsq   = (float*)alloc(128*4);
  int*      deg     = (int*)alloc((size_t)N*4);
  float*    pooled  = (float*)alloc((size_t)G*C2N*4);
  float*    cnt     = (float*)alloc((size_t)G*4);
  unsigned* almax1u = (unsigned*)alloc(16);
  unsigned* almax2u = (unsigned*)alloc(16);
  int*      csr_src = (int*)alloc((size_t)EPST*4);
  size_t Abytes = (size_t)(base - A0);
  // ---- region B: 0xFF (csr_dst = -1 marks pads) ----
  int*      csr_dst = (int*)alloc((size_t)EPST*4);
  // ---- rest ----
  float*   ab      = (float*)alloc(256*4);
  int*     rowptr  = (int*)alloc(((size_t)N+4)*4);
  int*     cursor  = (int*)alloc((size_t)N*4);
  int*     bsum    = (int*)alloc((size_t)nb*4);
  __half*  w1      = (__half*)alloc((size_t)4*EPST*2);
  __half*  h1      = (__half*)alloc((size_t)N*F1*2);
  __half*  x1      = (__half*)alloc((size_t)N*F1*2);
  float*   al1     = (float*)alloc((size_t)N*4*4);
  float*   ar1     = (float*)alloc((size_t)N*4*4);
  float*   h2      = (float*)alloc((size_t)N*C2N*4);
  float*   al2     = (float*)alloc((size_t)N*4);
  float*   ar2     = (float*)alloc((size_t)N*4);
  __half*  w2      = w1;   // alias plane 0: w1 dead after k_gat1

  hipMemsetAsync(A0, 0, Abytes, stream);
  hipMemsetAsync(csr_dst, 0xFF, (size_t)EPST*4, stream);

  k_bn_stats<<<512, 128, 0, stream>>>(x, sum, sumsq, N);
  k_bn_final<<<1, 128, 0, stream>>>(sum, sumsq, gam, bet, ab, N);
  k_deg<<<(Etot + 255)/256, 256, 0, stream>>>(ei, deg, E, Etot);
  k_scan_a<<<nb, 256, 0, stream>>>(deg, rowptr, bsum, N);
  k_scan_c<<<nb, 256, 0, stream>>>(rowptr, cursor, bsum, N);
  k_fill<<<(Etot + 255)/256, 256, 0, stream>>>(ei, cursor, csr_src, csr_dst, E, Etot);
  k_gemm1<<<(N + 7)/8, 128, 0, stream>>>(x, ab, W1, as1, ad1, h1, al1, ar1, N);
  k_colmax<<<128, 256, 0, stream>>>(al1, almax1u, N*4, 4);
  k_edge_w1<<<(EPST + 255)/256, 256, 0, stream>>>(csr_src, csr_dst, al1, ar1, almax1u, w1, EPST);
  k_gat1<<<(N + 3)/4, 256, 0, stream>>>(rowptr, csr_src, w1, h1, b1, x1, N, EPST);
  k_gemm2<<<(N + 31)/32, 256, 0, stream>>>(x1, W2, as2, ad2, h2, al2, ar2, N);
  k_colmax<<<64, 256, 0, stream>>>(al2, almax2u, N, 1);
  k_edge_w2<<<(EPST + 255)/256, 256, 0, stream>>>(csr_src, csr_dst, al2, ar2, almax2u, w2, EPST);
  k_gat2<<<(N + 31)/32, 256, 0, stream>>>(rowptr, csr_src, w2, h2, b2, batch, pooled, cnt, N);
  k_final<<<(G + 255)/256, 256, 0, stream>>>(pooled, cnt, (float*)d_out, G);
}